// Round 2
// baseline (38408.282 us; speedup 1.0000x reference)
//
#include <hip/hip_runtime.h>
#include <cstdint>
#include <cstddef>

#define H     1024
#define BATCH 16
#define SEQ   2000
#define NOUT  8
#define G     64       // persistent workgroups, 16 rows each
#define RPW   16
#define TPB   256

// d_out offsets (floats): n_all, h_all, r_all, u_all, z_all
#define N_OFF 0
#define H_OFF 32768000
#define R_OFF 65536000
#define U_OFF 98304000
#define Z_OFF 131072000

// ws layout (bytes)
#define FLAGS_OFF 0          // 64 flags padded to 32 uints (128B) each
#define SBUF_OFF  8192       // double-buffered s: 2 * 16*1024 floats
#define IREP_OFF  139264     // I repacked [t][b]
#define ZPART_OFF 267264     // zpart [t][g][b]

__global__ void init_kernel(const float* __restrict__ I, float* __restrict__ Irep,
                            unsigned int* __restrict__ flags) {
  int tid = blockIdx.x * blockDim.x + threadIdx.x;
  if (tid < SEQ * BATCH) {
    int t = tid >> 4, b = tid & 15;
    Irep[tid] = I[b * SEQ + t];            // I is [B, SEQ, 1]
  }
  if (tid < G) flags[tid * 32] = 0u;
}

__global__ __launch_bounds__(TPB, 1) void rnn_persist(
    const float* __restrict__ h0, const float* __restrict__ r0, const float* __restrict__ u0,
    const float* __restrict__ Wih, const float* __restrict__ offih,
    const float* __restrict__ Whh, const float* __restrict__ Whz,
    const float* __restrict__ prel, const float* __restrict__ Whhm, const float* __restrict__ Whzm,
    const float* __restrict__ Irep, float* __restrict__ sbuf, unsigned int* flags,
    float* __restrict__ zpart, float* __restrict__ dout)
{
  __shared__ float wL[RPW][H];       // 64KB masked W_hh rows (resident whole run)
  __shared__ float sL[BATCH][H];     // 64KB staged s_t
  __shared__ float recL[RPW * BATCH];

  const int g = blockIdx.x, tid = threadIdx.x;
  const int lane = tid & 63, w = tid >> 6;
  const int rt = w & 1, bt = w >> 1;          // matvec quadrant of this wave
  const int ro = tid & 15, bo = tid >> 4;     // state-owner mapping
  const int row = g * RPW + ro;

  // ---- one-time: stage masked recurrent weights into LDS ----
  {
    const float4* wsrc = (const float4*)(Whh + (size_t)g * RPW * H);
    const float4* msrc = (const float4*)(Whhm + (size_t)g * RPW * H);
    for (int k = tid; k < RPW * H / 4; k += TPB) {
      float4 wv = wsrc[k], mv = msrc[k];
      int rr = k >> 8, c = (k & 255) << 2;
      wL[rr][c]     = wv.x * mv.x;
      wL[rr][c + 1] = wv.y * mv.y;
      wL[rr][c + 2] = wv.z * mv.z;
      wL[rr][c + 3] = wv.w * mv.w;
    }
  }

  // ---- per-lane persistent state ----
  const int sidx = bo * H + row;
  float h  = h0[sidx], rr_ = r0[sidx], u = u0[sidx];
  float p  = prel[row], psyn = 1.0f / p;
  float wih = Wih[row], oih = offih[row];
  const int o = row >> 7;
  float wz = Whz[o * H + row] * Whzm[o * H + row];
  float ht = 1.0f / (1.0f + expf(-8.0f * (h - 0.5f)));

  // publish s_0 (agent-scope atomic stores bypass non-coherent L2s)
  __hip_atomic_store(&sbuf[sidx], ht * rr_ * u * psyn,
                     __ATOMIC_RELAXED, __HIP_MEMORY_SCOPE_AGENT);
  asm volatile("s_waitcnt vmcnt(0)" ::: "memory");
  __syncthreads();
  if (tid == 0)
    __hip_atomic_store(&flags[g * 32], 1u, __ATOMIC_RELAXED, __HIP_MEMORY_SCOPE_AGENT);

  float* outh = dout + H_OFF + (size_t)bo * (SEQ * H) + row;
  float* outr = dout + R_OFF + (size_t)bo * (SEQ * H) + row;
  float* outu = dout + U_OFF + (size_t)bo * (SEQ * H) + row;

  for (int t = 0; t < SEQ; ++t) {
    // ---- wait for all WGs' s_t (wave 0 polls the 64 flags) ----
    if (tid < 64) {
      const unsigned int tgt = (unsigned int)(t + 1);
      unsigned int* f = flags + (tid << 5);
      for (int it = 0; it < (1 << 16); ++it) {
        if (__hip_atomic_load(f, __ATOMIC_RELAXED, __HIP_MEMORY_SCOPE_AGENT) >= tgt) break;
      }
    }
    __syncthreads();   // nobody stages until every flag confirmed

    // ---- stage s_t into LDS (agent-scope loads: always fresh) ----
    const float* sb = sbuf + (t & 1) * (BATCH * H);
    #pragma unroll
    for (int k = 0; k < 64; ++k) {
      int idx = k * TPB + tid;
      float v = __hip_atomic_load(sb + idx, __ATOMIC_RELAXED, __HIP_MEMORY_SCOPE_AGENT);
      sL[idx >> 10][idx & 1023] = v;
    }
    __syncthreads();

    // ---- matvec: 8x8 outputs per thread, 64-way j-split per wave ----
    float acc[8][8];
    #pragma unroll
    for (int i = 0; i < 8; ++i)
      #pragma unroll
      for (int j = 0; j < 8; ++j) acc[i][j] = 0.0f;

    #pragma unroll
    for (int c = 0; c < 4; ++c) {
      const int c4 = lane + 64 * c;            // float4 column index
      float4 wv[8], sv[8];
      #pragma unroll
      for (int i = 0; i < 8; ++i)  wv[i] = ((const float4*)wL[rt * 8 + i])[c4];
      #pragma unroll
      for (int i = 0; i < 8; ++i)  sv[i] = ((const float4*)sL[bt * 8 + i])[c4];
      #pragma unroll
      for (int i = 0; i < 8; ++i)
        #pragma unroll
        for (int j = 0; j < 8; ++j) {
          acc[i][j] = fmaf(wv[i].x, sv[j].x, acc[i][j]);
          acc[i][j] = fmaf(wv[i].y, sv[j].y, acc[i][j]);
          acc[i][j] = fmaf(wv[i].z, sv[j].z, acc[i][j]);
          acc[i][j] = fmaf(wv[i].w, sv[j].w, acc[i][j]);
        }
    }

    // ---- in-register butterfly: sum each output over the 64 lanes ----
    float v[64];
    #pragma unroll
    for (int i = 0; i < 8; ++i)
      #pragma unroll
      for (int j = 0; j < 8; ++j) v[i * 8 + j] = acc[i][j];
    #pragma unroll
    for (int k = 0; k < 6; ++k) {
      const int d = 1 << k;
      const bool bit = (lane >> k) & 1;
      #pragma unroll
      for (int m = 0; m < (32 >> k); ++m) {
        float a = v[2 * m], b2 = v[2 * m + 1];
        float send = bit ? a : b2;
        float keep = bit ? b2 : a;
        v[m] = keep + __shfl_xor(send, d);
      }
    }
    // lane l now holds rec for output (r = rt*8 + (l>>3), b = bt*8 + (l&7))
    recL[(rt * 8 + (lane >> 3)) * 16 + (bt * 8 + (lane & 7))] = v[0];
    __syncthreads();
    float rec = recL[ro * 16 + bo];

    // ---- state update (same op order as reference; n == 0 always) ----
    float It  = Irep[t * BATCH + bo];
    float ext = It * wih + oih;
    float hn  = h + ((-h + rec + ext) / 0.01f) * 0.001f;
    float htn = 1.0f / (1.0f + expf(-8.0f * (hn - 0.5f)));
    float rn  = rr_ + ((1.0f - rr_) / 0.2f - 50.0f * u * rr_ * ht) * 0.001f;
    float un  = u + ((p - u) / 1.5f + 50.0f * p * (1.0f - u) * ht) * 0.001f;

    // ---- publish s_{t+1} FIRST (critical path), outputs after ----
    float sn = htn * rn * un * psyn;
    __hip_atomic_store(&sbuf[((t + 1) & 1) * (BATCH * H) + sidx], sn,
                       __ATOMIC_RELAXED, __HIP_MEMORY_SCOPE_AGENT);
    asm volatile("s_waitcnt vmcnt(0)" ::: "memory");
    __syncthreads();   // all waves' s stores retired
    if (tid == 0)
      __hip_atomic_store(&flags[g * 32], (unsigned int)(t + 2),
                         __ATOMIC_RELAXED, __HIP_MEMORY_SCOPE_AGENT);

    outh[t * H] = hn; outr[t * H] = rn; outu[t * H] = un;

    float zl = htn * wz;
    zl += __shfl_xor(zl, 1); zl += __shfl_xor(zl, 2);
    zl += __shfl_xor(zl, 4); zl += __shfl_xor(zl, 8);
    if (ro == 0) zpart[((size_t)t * G + g) * BATCH + bo] = zl;

    h = hn; ht = htn; rr_ = rn; u = un;
  }
}

__global__ void zred_kernel(const float* __restrict__ zpart, const float* __restrict__ offhz,
                            float* __restrict__ zout) {
  int tid = blockIdx.x * blockDim.x + threadIdx.x;
  if (tid >= BATCH * SEQ * NOUT) return;
  int b = tid / (SEQ * NOUT);
  int rem = tid - b * (SEQ * NOUT);
  int t = rem >> 3, o = rem & 7;
  float acc = offhz[o];
  #pragma unroll
  for (int k = 0; k < G / NOUT; ++k)
    acc += zpart[((size_t)t * G + o * (G / NOUT) + k) * BATCH + b];
  zout[tid] = acc;
}

extern "C" void kernel_launch(void* const* d_in, const int* in_sizes, int n_in,
                              void* d_out, int out_size, void* d_ws, size_t ws_size,
                              hipStream_t stream) {
  const float* I     = (const float*)d_in[0];
  const float* h0    = (const float*)d_in[1];
  const float* r0    = (const float*)d_in[2];
  const float* u0    = (const float*)d_in[3];
  const float* Wih   = (const float*)d_in[4];
  const float* offih = (const float*)d_in[5];
  const float* Whh   = (const float*)d_in[6];
  const float* Whz   = (const float*)d_in[7];
  const float* offhz = (const float*)d_in[8];
  const float* prel  = (const float*)d_in[9];
  const float* Whhm  = (const float*)d_in[10];
  const float* Whzm  = (const float*)d_in[11];
  float* out = (float*)d_out;

  unsigned int* flags = (unsigned int*)((char*)d_ws + FLAGS_OFF);
  float* sbuf  = (float*)((char*)d_ws + SBUF_OFF);
  float* Irep  = (float*)((char*)d_ws + IREP_OFF);
  float* zpart = (float*)((char*)d_ws + ZPART_OFF);

  hipMemsetAsync(d_out, 0, (size_t)H_OFF * sizeof(float), stream);  // n_all == 0
  init_kernel<<<(SEQ * BATCH + 255) / 256, 256, 0, stream>>>(I, Irep, flags);
  rnn_persist<<<G, TPB, 0, stream>>>(h0, r0, u0, Wih, offih, Whh, Whz, prel, Whhm, Whzm,
                                     Irep, sbuf, flags, zpart, out);
  zred_kernel<<<(BATCH * SEQ * NOUT + 255) / 256, 256, 0, stream>>>(zpart, offhz, out + Z_OFF);
}

// Round 3
// 11934.960 us; speedup vs baseline: 3.2181x; 3.2181x over previous
//
#include <hip/hip_runtime.h>
#include <cstdint>
#include <cstddef>

typedef float f32x4 __attribute__((ext_vector_type(4)));

#define H     1024
#define BATCH 16
#define SEQ   2000
#define NOUT  8
#define G     64       // persistent workgroups, 16 rows each
#define RPW   16
#define TPB   256

// d_out offsets (floats): n_all, h_all, r_all, u_all, z_all
#define N_OFF 0
#define H_OFF 32768000
#define R_OFF 65536000
#define U_OFF 98304000
#define Z_OFF 131072000

// ws layout (bytes)
#define FLAGS_OFF 0          // 64 counters padded to 32 uints (128B) each
#define SBUF_OFF  8192       // double-buffered s: 2 * 16*1024 floats, layout [b][row]
#define IREP_OFF  139264     // I repacked [t][b] (+64B pad for prefetch overrun)
#define ZPART_OFF 267328     // zpart [t][g][b]

__global__ void init_kernel(const float* __restrict__ I, float* __restrict__ Irep,
                            unsigned int* __restrict__ flags) {
  int tid = blockIdx.x * blockDim.x + threadIdx.x;
  if (tid < SEQ * BATCH) {
    int t = tid >> 4, b = tid & 15;
    Irep[tid] = I[b * SEQ + t];            // I is [B, SEQ, 1]
  }
  if (tid < G) flags[tid * 32] = 0u;
}

__global__ __launch_bounds__(TPB, 1) void rnn_persist(
    const float* __restrict__ h0, const float* __restrict__ r0, const float* __restrict__ u0,
    const float* __restrict__ Wih, const float* __restrict__ offih,
    const float* __restrict__ Whh, const float* __restrict__ Whz,
    const float* __restrict__ prel, const float* __restrict__ Whhm, const float* __restrict__ Whzm,
    const float* __restrict__ Irep, float* __restrict__ sbuf, unsigned int* __restrict__ flags,
    float* __restrict__ zpart, float* __restrict__ dout)
{
  __shared__ float wL[RPW][H];   // 64KB masked W_hh rows, resident all 2000 steps

  const int g = blockIdx.x, tid = threadIdx.x;
  const int lane = tid & 63, w = tid >> 6;
  const int ro = lane >> 2;              // row within WG   (butterfly output = lane)
  const int bo = (w << 2) + (lane & 3);  // batch owned by this lane
  const int row = g * RPW + ro;

  // ---- one-time: masked W_hh rows -> LDS ----
  {
    const f32x4* wsrc = (const f32x4*)(Whh + (size_t)g * RPW * H);
    const f32x4* msrc = (const f32x4*)(Whhm + (size_t)g * RPW * H);
    for (int k = tid; k < RPW * H / 4; k += TPB)
      ((f32x4*)&wL[0][0])[k] = wsrc[k] * msrc[k];
  }
  __syncthreads();   // only barrier in the whole kernel

  // ---- per-lane persistent state ----
  const int sidx = bo * H + row;         // sbuf layout [b][row]
  float h  = h0[sidx], rr_ = r0[sidx], u = u0[sidx];
  float p  = prel[row], psyn = 1.0f / p;
  float wih = Wih[row], oih = offih[row];
  const int o = row >> 7;
  float wz = Whz[o * H + row] * Whzm[o * H + row];
  float ht = 1.0f / (1.0f + __expf(-8.0f * (h - 0.5f)));

  const float INV_TAU = 1.0f / 0.01f, INV_TD = 1.0f / 0.2f, INV_TF = 1.0f / 1.5f;

  // ---- publish s_0 (system-scope write-through), then count this wave in ----
  {
    float s0 = ht * rr_ * u * psyn;
    float* ap = sbuf + sidx;
    asm volatile("global_store_dword %0, %1, off sc0 sc1" :: "v"(ap), "v"(s0) : "memory");
    asm volatile("s_waitcnt vmcnt(0)" ::: "memory");
    if (lane == 0)
      __hip_atomic_fetch_add(&flags[g * 32], 1u, __ATOMIC_RELAXED, __HIP_MEMORY_SCOPE_AGENT);
  }

  float* ph = dout + H_OFF + (size_t)bo * (SEQ * H) + row;
  float* pr = dout + R_OFF + (size_t)bo * (SEQ * H) + row;
  float* pu = dout + U_OFF + (size_t)bo * (SEQ * H) + row;
  float* pz = zpart + (size_t)g * BATCH + (w << 2) + lane;  // valid when lane < 4
  const float* ip = Irep + bo;
  float Itc = ip[0];                      // prefetched I_t

#define ISSUE(c) { _Pragma("unroll") for (int m = 0; m < 4; ++m) { \
    const float* ap = sb + ((w << 2) + m) * H + (c) * 256 + (lane << 2); \
    asm volatile("global_load_dwordx4 %0, %1, off sc0 sc1" : "=v"(ld[c][m]) : "v"(ap)); } }

#define DO_CHUNK(c) { const int c4 = (c) * 64 + lane; \
  _Pragma("unroll") for (int i = 0; i < 16; ++i) { \
    f32x4 wv = ((const f32x4*)&wL[i][0])[c4]; \
    _Pragma("unroll") for (int m = 0; m < 4; ++m) { \
      float a = acc[i * 4 + m]; f32x4 sv = ld[c][m]; \
      a = fmaf(wv.x, sv.x, a); a = fmaf(wv.y, sv.y, a); \
      a = fmaf(wv.z, sv.z, a); a = fmaf(wv.w, sv.w, a); \
      acc[i * 4 + m] = a; } } }

#define WAITV(n) { asm volatile("s_waitcnt vmcnt(" #n ")" ::: "memory"); \
                   __builtin_amdgcn_sched_barrier(0); }

  for (int t = 0; t < SEQ; ++t) {
    // ---- wait until every WG has published s_t (4 waves each) ----
    const unsigned int tgt = 4u * (unsigned int)(t + 1);
    for (int it = 0; it < (1 << 16); ++it) {
      unsigned int f = __hip_atomic_load(&flags[(size_t)lane << 5],
                                         __ATOMIC_RELAXED, __HIP_MEMORY_SCOPE_AGENT);
      if (__all((int)(f >= tgt))) break;
    }
    asm volatile("s_waitcnt vmcnt(0)" ::: "memory");   // drain prior stores/prefetch
    __builtin_amdgcn_sched_barrier(0);

    // ---- fetch s_t for this wave's 4 batches, 2-chunk-deep pipeline ----
    const float* sb = sbuf + (t & 1) * (BATCH * H);
    f32x4 ld[4][4];
    float acc[64];
    #pragma unroll
    for (int q = 0; q < 64; ++q) acc[q] = 0.0f;

    ISSUE(0); ISSUE(1);
    WAITV(4);  DO_CHUNK(0);  ISSUE(2);
    WAITV(4);  DO_CHUNK(1);  ISSUE(3);
    WAITV(4);  DO_CHUNK(2);
    WAITV(0);  DO_CHUNK(3);

    // ---- butterfly: sum 64 j-slices; lane l ends with output (ro=l>>2, m=l&3) ----
    #pragma unroll
    for (int k = 0; k < 6; ++k) {
      const int d = 1 << k;
      const bool bit = (lane >> k) & 1;
      #pragma unroll
      for (int m = 0; m < (32 >> k); ++m) {
        float a = acc[2 * m], b2 = acc[2 * m + 1];
        float send = bit ? a : b2;
        float keep = bit ? b2 : a;
        acc[m] = keep + __shfl_xor(send, d);
      }
    }
    float rec = acc[0];

    // ---- state update (n == 0 identically) ----
    float ext = Itc * wih + oih;
    float hn  = h + ((-h + rec + ext) * INV_TAU) * 0.001f;
    float htn = 1.0f / (1.0f + __expf(-8.0f * (hn - 0.5f)));
    float rn  = rr_ + ((1.0f - rr_) * INV_TD - 50.0f * u * rr_ * ht) * 0.001f;
    float un  = u + ((p - u) * INV_TF + 50.0f * p * (1.0f - u) * ht) * 0.001f;

    // ---- publish s_{t+1} first (critical path) ----
    float sn = htn * rn * un * psyn;
    {
      float* ap = sbuf + ((t + 1) & 1) * (BATCH * H) + sidx;
      asm volatile("global_store_dword %0, %1, off sc0 sc1" :: "v"(ap), "v"(sn) : "memory");
      asm volatile("s_waitcnt vmcnt(0)" ::: "memory");
      if (lane == 0)
        __hip_atomic_fetch_add(&flags[g * 32], 1u, __ATOMIC_RELAXED, __HIP_MEMORY_SCOPE_AGENT);
    }

    // ---- outputs (overlap other WGs' polling) ----
    ph[(size_t)t * H] = hn; pr[(size_t)t * H] = rn; pu[(size_t)t * H] = un;
    float zl = htn * wz;
    zl += __shfl_xor(zl, 4); zl += __shfl_xor(zl, 8);
    zl += __shfl_xor(zl, 16); zl += __shfl_xor(zl, 32);
    if (lane < 4) pz[(size_t)t * (G * BATCH)] = zl;

    Itc = ip[(size_t)(t + 1) * BATCH];   // prefetch next I (64B pad covers t+1==SEQ)
    h = hn; ht = htn; rr_ = rn; u = un;
  }
#undef ISSUE
#undef DO_CHUNK
#undef WAITV
}

__global__ void zred_kernel(const float* __restrict__ zpart, const float* __restrict__ offhz,
                            float* __restrict__ zout) {
  int tid = blockIdx.x * blockDim.x + threadIdx.x;
  if (tid >= BATCH * SEQ * NOUT) return;
  int b = tid / (SEQ * NOUT);
  int rem = tid - b * (SEQ * NOUT);
  int t = rem >> 3, o = rem & 7;
  float acc = offhz[o];
  #pragma unroll
  for (int k = 0; k < G / NOUT; ++k)
    acc += zpart[((size_t)t * G + o * (G / NOUT) + k) * BATCH + b];
  zout[tid] = acc;
}

extern "C" void kernel_launch(void* const* d_in, const int* in_sizes, int n_in,
                              void* d_out, int out_size, void* d_ws, size_t ws_size,
                              hipStream_t stream) {
  const float* I     = (const float*)d_in[0];
  const float* h0    = (const float*)d_in[1];
  const float* r0    = (const float*)d_in[2];
  const float* u0    = (const float*)d_in[3];
  const float* Wih   = (const float*)d_in[4];
  const float* offih = (const float*)d_in[5];
  const float* Whh   = (const float*)d_in[6];
  const float* Whz   = (const float*)d_in[7];
  const float* offhz = (const float*)d_in[8];
  const float* prel  = (const float*)d_in[9];
  const float* Whhm  = (const float*)d_in[10];
  const float* Whzm  = (const float*)d_in[11];
  float* out = (float*)d_out;

  unsigned int* flags = (unsigned int*)((char*)d_ws + FLAGS_OFF);
  float* sbuf  = (float*)((char*)d_ws + SBUF_OFF);
  float* Irep  = (float*)((char*)d_ws + IREP_OFF);
  float* zpart = (float*)((char*)d_ws + ZPART_OFF);

  hipMemsetAsync(d_out, 0, (size_t)H_OFF * sizeof(float), stream);  // n_all == 0
  init_kernel<<<(SEQ * BATCH + 255) / 256, 256, 0, stream>>>(I, Irep, flags);
  rnn_persist<<<G, TPB, 0, stream>>>(h0, r0, u0, Wih, offih, Whh, Whz, prel, Whhm, Whzm,
                                     Irep, sbuf, flags, zpart, out);
  zred_kernel<<<(BATCH * SEQ * NOUT + 255) / 256, 256, 0, stream>>>(zpart, offhz, out + Z_OFF);
}